// Round 1
// baseline (28.962 us; speedup 1.0000x reference)
//
#include <hip/hip_runtime.h>
#include <stdint.h>

#define ONE_BITS    0x3f800000u
#define NEGONE_BITS 0xbf800000u

// Cells where placing a piece of `P`'s color completes 4-in-a-row, any direction.
// Layout: bit = r*8 + c, r=0 top .. 5 bottom, c=0..6, col 7 = zero guard column.
static __device__ __forceinline__ uint64_t win_cells(uint64_t P) {
    uint64_t w = 0;
    #pragma unroll
    for (int d = 0; d < 4; ++d) {
        const int s = (d == 0) ? 1 : (d == 1) ? 7 : (d == 2) ? 8 : 9;
        uint64_t r1 = P >> s, r2 = P >> (2 * s), r3 = P >> (3 * s);
        uint64_t l1 = P << s, l2 = P << (2 * s), l3 = P << (3 * s);
        uint64_t a = r1 & r2;   // cells with next-two in +dir set
        uint64_t b = l1 & l2;   // cells with prev-two in -dir set
        // q wins as window position 0 / 1 / 2 / 3 respectively:
        w |= (a & r3) | (a & l1) | (b & r1) | (b & l3);
    }
    return w;
}

// OR all 6 rows down into the low 7 bits (one bit per column).
static __device__ __forceinline__ uint32_t colfold(uint64_t v) {
    v |= v >> 8;
    v |= v >> 16;
    v |= v >> 32;
    return (uint32_t)v & 0x7Fu;
}

extern "C" __global__ void __launch_bounds__(256)
c4_kernel(const float* __restrict__ x, float* __restrict__ out, int npairs)
{
    int t = blockIdx.x * blockDim.x + threadIdx.x;
    if (t >= npairs) return;

    // 2 boards per thread -> 84 floats = 336 B = 21 aligned float4 loads.
    const float4* src = reinterpret_cast<const float4*>(x) + (size_t)t * 21u;

    uint32_t plo[2] = {0, 0}, phi[2] = {0, 0};
    uint32_t mlo[2] = {0, 0}, mhi[2] = {0, 0};

    #pragma unroll
    for (int k = 0; k < 21; ++k) {
        float4 v = src[k];
        uint32_t uu[4] = { __float_as_uint(v.x), __float_as_uint(v.y),
                           __float_as_uint(v.z), __float_as_uint(v.w) };
        #pragma unroll
        for (int j = 0; j < 4; ++j) {
            const int cell = 4 * k + j;       // 0..83, compile-time
            const int b    = (cell >= 42) ? 1 : 0;
            const int idx  = cell - 42 * b;   // 0..41 within board
            const int sh   = (idx / 7) * 8 + (idx % 7);  // r*8 + c
            uint32_t isP = (uu[j] == ONE_BITS)    ? 1u : 0u;
            uint32_t isM = (uu[j] == NEGONE_BITS) ? 1u : 0u;
            if (sh < 32) {
                plo[b] |= isP << sh;
                mlo[b] |= isM << sh;
            } else {
                phi[b] |= isP << (sh - 32);
                mhi[b] |= isM << (sh - 32);
            }
        }
    }

    float vals[14];
    #pragma unroll
    for (int b = 0; b < 2; ++b) {
        uint64_t P   = (uint64_t)plo[b] | ((uint64_t)phi[b] << 32);
        uint64_t M   = (uint64_t)mlo[b] | ((uint64_t)mhi[b] << 32);
        uint64_t occ = P | M;
        const uint64_t BOARD = 0x00007F7F7F7F7F7FULL;  // rows 0..5, cols 0..6
        const uint64_t ROW5  = 0x00007F0000000000ULL;  // bottom row
        // Landing cell per column: empty AND (cell below occupied OR bottom row).
        uint64_t land = ~occ & BOARD & ((occ >> 8) | ROW5);

        uint32_t cp = colfold(land & win_cells(P));  // +1 winning columns
        uint32_t cm = colfold(land & win_cells(M));  // -1 winning columns
        uint32_t sel = cp ? cp : cm;                 // +1 takes precedence
        bool any = (sel != 0u);
        int col  = __ffs(sel) - 1;                   // lowest winning column

        #pragma unroll
        for (int c = 0; c < 7; ++c)
            vals[7 * b + c] = (any && c != col) ? -27.631021f : 0.0f;
    }

    float2* o2 = reinterpret_cast<float2*>(out) + (size_t)t * 7u;
    #pragma unroll
    for (int i = 0; i < 7; ++i)
        o2[i] = make_float2(vals[2 * i], vals[2 * i + 1]);
}

extern "C" void kernel_launch(void* const* d_in, const int* in_sizes, int n_in,
                              void* d_out, int out_size, void* d_ws, size_t ws_size,
                              hipStream_t stream)
{
    const float* x = (const float*)d_in[0];
    float* out = (float*)d_out;
    const int N = in_sizes[0] / 42;       // boards
    const int npairs = N / 2;             // 2 boards per thread (N is even)
    const int block = 256;
    const int grid = (npairs + block - 1) / block;
    hipLaunchKernelGGL(c4_kernel, dim3(grid), dim3(block), 0, stream,
                       x, out, npairs);
}

// Round 2
// 21.771 us; speedup vs baseline: 1.3303x; 1.3303x over previous
//
#include <hip/hip_runtime.h>
#include <stdint.h>

#define ONE_BITS    0x3f800000u
#define NEGONE_BITS 0xbf800000u

#define THREADS 256
#define BOARDS_PER_BLOCK 256   // 1 board per thread

// Cells where placing a piece of `P`'s color completes 4-in-a-row, any direction.
// Layout: bit = r*8 + c, r=0 top .. 5 bottom, c=0..6, col 7 = zero guard column.
static __device__ __forceinline__ uint64_t win_cells(uint64_t P) {
    uint64_t w = 0;
    #pragma unroll
    for (int d = 0; d < 4; ++d) {
        const int s = (d == 0) ? 1 : (d == 1) ? 7 : (d == 2) ? 8 : 9;
        uint64_t r1 = P >> s, r2 = P >> (2 * s), r3 = P >> (3 * s);
        uint64_t l1 = P << s, l2 = P << (2 * s), l3 = P << (3 * s);
        uint64_t a = r1 & r2;   // next-two in +dir set
        uint64_t b = l1 & l2;   // prev-two in -dir set
        w |= (a & r3) | (a & l1) | (b & r1) | (b & l3);
    }
    return w;
}

// OR all 6 rows down into the low 7 bits (one bit per column).
static __device__ __forceinline__ uint32_t colfold(uint64_t v) {
    v |= v >> 8;
    v |= v >> 16;
    v |= v >> 32;
    return (uint32_t)v & 0x7Fu;
}

extern "C" __global__ void __launch_bounds__(256)
c4_kernel(const float* __restrict__ x, float* __restrict__ out)
{
    __shared__ float s_in[BOARDS_PER_BLOCK * 42];  // 43008 B
    __shared__ float s_out[BOARDS_PER_BLOCK * 7];  //  7168 B

    const int tid = threadIdx.x;
    const size_t board0 = (size_t)blockIdx.x * BOARDS_PER_BLOCK;

    // ---- coalesced global -> LDS: 5376 float2 per block, 21 per thread ----
    const float2* src = reinterpret_cast<const float2*>(x) + board0 * 21u;
    float2* sin2 = reinterpret_cast<float2*>(s_in);
    #pragma unroll
    for (int k = 0; k < 21; ++k) {
        int n = k * THREADS + tid;          // lane-consecutive: 512B/wave-instr
        sin2[n] = src[n];
    }
    __syncthreads();

    // ---- build bitboards from this thread's own 168B LDS row ----
    const float* my = s_in + tid * 42;
    uint32_t plo = 0, phi = 0, mlo = 0, mhi = 0;
    #pragma unroll
    for (int idx = 0; idx < 42; ++idx) {
        uint32_t u = __float_as_uint(my[idx]);
        const int sh = (idx / 7) * 8 + (idx % 7);   // r*8 + c, compile-time
        uint32_t isP = (u == ONE_BITS)    ? 1u : 0u;
        uint32_t isM = (u == NEGONE_BITS) ? 1u : 0u;
        if (sh < 32) { plo |= isP << sh;        mlo |= isM << sh; }
        else         { phi |= isP << (sh - 32); mhi |= isM << (sh - 32); }
    }

    uint64_t P   = (uint64_t)plo | ((uint64_t)phi << 32);
    uint64_t M   = (uint64_t)mlo | ((uint64_t)mhi << 32);
    uint64_t occ = P | M;
    const uint64_t BOARD = 0x00007F7F7F7F7F7FULL;  // rows 0..5, cols 0..6
    const uint64_t ROW5  = 0x00007F0000000000ULL;  // bottom row
    // Landing cell per column: empty AND (cell below occupied OR bottom row).
    uint64_t land = ~occ & BOARD & ((occ >> 8) | ROW5);

    uint32_t cp = colfold(land & win_cells(P));    // +1 winning columns
    uint32_t cm = colfold(land & win_cells(M));    // -1 winning columns
    uint32_t sel = cp ? cp : cm;                   // +1 takes precedence
    bool any = (sel != 0u);
    int col  = __ffs(sel) - 1;                     // lowest winning column

    #pragma unroll
    for (int c = 0; c < 7; ++c)
        s_out[tid * 7 + c] = (any && c != col) ? -27.631021f : 0.0f;
    __syncthreads();

    // ---- coalesced LDS -> global: 1792 floats per block ----
    float* dst = out + board0 * 7u;
    #pragma unroll
    for (int k = 0; k < 7; ++k) {
        int n = k * THREADS + tid;          // lane-consecutive: 1KB/wave-instr
        dst[n] = s_out[n];
    }
}

extern "C" void kernel_launch(void* const* d_in, const int* in_sizes, int n_in,
                              void* d_out, int out_size, void* d_ws, size_t ws_size,
                              hipStream_t stream)
{
    const float* x = (const float*)d_in[0];
    float* out = (float*)d_out;
    const int N = in_sizes[0] / 42;                   // boards (524288)
    const int grid = N / BOARDS_PER_BLOCK;            // 2048
    hipLaunchKernelGGL(c4_kernel, dim3(grid), dim3(THREADS), 0, stream, x, out);
}

// Round 3
// 21.547 us; speedup vs baseline: 1.3441x; 1.0104x over previous
//
#include <hip/hip_runtime.h>
#include <stdint.h>

#define THREADS 256
#define BOARDS_PER_BLOCK 512   // 2 boards per thread

// Column-range mask in 7-wide layout: bit = 7*r + c, r=0 top .. 5 bottom.
static constexpr uint64_t colmask(int lo, int hi) {
    uint64_t m = 0;
    for (int r = 0; r < 6; ++r)
        for (int c = lo; c <= hi; ++c)
            m |= 1ull << (7 * r + c);
    return m;
}

// Cells where placing a piece of `P`'s color completes 4-in-a-row.
// 7-wide layout; column-wrap handled by per-term column masks (they nest,
// so each 3-input term needs exactly one mask AND).
static __device__ __forceinline__ uint64_t win_cells(uint64_t P) {
    uint64_t w = 0;
    #pragma unroll
    for (int d = 0; d < 4; ++d) {
        const int s  = (d == 0) ? 1 : (d == 1) ? 7 : (d == 2) ? 8 : 6;
        const int dc = (d == 0) ? 1 : (d == 1) ? 0 : (d == 2) ? 1 : -1;
        // window position p: col constraint c+(3-p)*dc in [0,6] and c-p*dc in [0,6]
        const uint64_t M0 = (dc == 0) ? ~0ull : (dc > 0 ? colmask(0, 3) : colmask(3, 6));
        const uint64_t M1 = (dc == 0) ? ~0ull : (dc > 0 ? colmask(1, 4) : colmask(2, 5));
        const uint64_t M2 = (dc == 0) ? ~0ull : (dc > 0 ? colmask(2, 5) : colmask(1, 4));
        const uint64_t M3 = (dc == 0) ? ~0ull : (dc > 0 ? colmask(3, 6) : colmask(0, 3));
        uint64_t r1 = P >> s, r2 = P >> (2 * s), r3 = P >> (3 * s);
        uint64_t l1 = P << s, l2 = P << (2 * s), l3 = P << (3 * s);
        uint64_t u = r1 & r2, v = l1 & l2;
        w |= (u & r3 & M0) | (u & l1 & M1) | (v & r1 & M2) | (v & l3 & M3);
    }
    return w;
}

// OR all 6 rows (period 7) into the low 7 bits.
static __device__ __forceinline__ uint32_t colfold(uint64_t v) {
    v |= v >> 21;
    v |= v >> 7;
    v |= v >> 7;
    return (uint32_t)v & 0x7Fu;
}

extern "C" __global__ void __launch_bounds__(THREADS)
c4_kernel(const float* __restrict__ x, float* __restrict__ out)
{
    __shared__ uint32_t s_pk[BOARDS_PER_BLOCK * 42 / 4];  // 5376 dwords = 21504 B
    __shared__ float    s_out[BOARDS_PER_BLOCK * 7];      // 14336 B

    const int tid = threadIdx.x;
    const size_t board0 = (size_t)blockIdx.x * BOARDS_PER_BLOCK;

    // ---- coalesced global -> LDS, compressing each cell to its top byte ----
    // bit5 (0x20): cell occupied (0x3f / 0xbf), bit7 (0x80): cell is -1 (0xbf)
    const float4* src = reinterpret_cast<const float4*>(x) + (size_t)blockIdx.x * 5376u;
    #pragma unroll
    for (int k = 0; k < 21; ++k) {
        int n = k * THREADS + tid;              // lane-consecutive 16B loads
        float4 v = src[n];
        uint32_t a = __float_as_uint(v.x), b = __float_as_uint(v.y),
                 c = __float_as_uint(v.z), d = __float_as_uint(v.w);
        // pack [top(a), top(b), top(c), top(d)] via 2x v_perm_b32
        uint32_t lo = __builtin_amdgcn_perm(b, a, 0x00000703u) & 0x0000FFFFu;
        uint32_t hi = __builtin_amdgcn_perm(d, c, 0x07030000u) & 0xFFFF0000u;
        s_pk[n] = lo | hi;                      // dword n = cells 4n..4n+3
    }
    __syncthreads();

    // ---- per-thread: 21 aligned dwords = 2 boards' 84 cell-bytes ----
    const uint32_t* pk = s_pk + tid * 21;       // byte offset 84*tid, aligned
    uint64_t occ[2] = {0, 0}, MM[2] = {0, 0};
    #pragma unroll
    for (int j = 0; j < 21; ++j) {
        uint32_t e = pk[j];
        // movmskb-style gather: 4 byte-flags -> 4 consecutive bits (carry-free)
        uint32_t nO = ((e & 0x20202020u) * 0x00204081u) >> 26;  // occupied
        uint32_t nM = ((e & 0x80808080u) * 0x00204081u) >> 28;  // minus
        if (j < 10) {
            occ[0] |= (uint64_t)nO << (4 * j);
            MM[0]  |= (uint64_t)nM << (4 * j);
        } else if (j == 10) {                   // cells 40,41 | 42,43 straddle
            occ[0] |= (uint64_t)(nO & 3u) << 40;
            MM[0]  |= (uint64_t)(nM & 3u) << 40;
            occ[1] |= (uint64_t)(nO >> 2);
            MM[1]  |= (uint64_t)(nM >> 2);
        } else {
            occ[1] |= (uint64_t)nO << (4 * j - 42);
            MM[1]  |= (uint64_t)nM << (4 * j - 42);
        }
    }

    #pragma unroll
    for (int b = 0; b < 2; ++b) {
        uint64_t o = occ[b], m = MM[b], p = o & ~m;
        const uint64_t ROW5 = 0x7Full << 35;    // bottom row
        uint64_t land = ~o & ((o >> 7) | ROW5); // landing cell per column

        uint32_t cp = colfold(land & win_cells(p));  // +1 winning columns
        uint32_t cm = colfold(land & win_cells(m));  // -1 winning columns
        uint32_t sel = cp ? cp : cm;                 // +1 takes precedence
        bool any = (sel != 0u);
        int col  = __ffs(sel) - 1;                   // lowest winning column

        float* so = s_out + (2 * tid + b) * 7;
        #pragma unroll
        for (int c = 0; c < 7; ++c)
            so[c] = (any && c != col) ? -27.631021f : 0.0f;
    }
    __syncthreads();

    // ---- coalesced LDS -> global: 3584 floats per block ----
    float* dst = out + board0 * 7u;
    #pragma unroll
    for (int k = 0; k < 14; ++k) {
        int n = k * THREADS + tid;
        dst[n] = s_out[n];
    }
}

extern "C" void kernel_launch(void* const* d_in, const int* in_sizes, int n_in,
                              void* d_out, int out_size, void* d_ws, size_t ws_size,
                              hipStream_t stream)
{
    const float* x = (const float*)d_in[0];
    float* out = (float*)d_out;
    const int N = in_sizes[0] / 42;                 // 524288 boards
    const int grid = N / BOARDS_PER_BLOCK;          // 1024 blocks = 4 per CU
    hipLaunchKernelGGL(c4_kernel, dim3(grid), dim3(THREADS), 0, stream, x, out);
}